// Round 1
// baseline (614.293 us; speedup 1.0000x reference)
//
#include <hip/hip_runtime.h>
#include <hip/hip_bf16.h>

#define BB 8
#define NN 65536
#define CC 64
#define MM 64

#define TWO_PI 6.283185307179586476925286766559f

// ---------------- Pass 1: projection ----------------
// coeffs_acc[b][c][ri][m] += { cos(ph)*x , -sin(ph)*x }  (division by N deferred)
// grid = BB*CHUNKS1 blocks of 256. lane = mode m, wave = 16-channel group.
#define CHUNKS1 128
#define PTS1 (NN / CHUNKS1) // 512 points per block

__global__ __launch_bounds__(256) void proj_kernel(
    const float* __restrict__ inputs,   // [B][N][C]
    const float* __restrict__ coords,   // [B][N][2]
    const float* __restrict__ freqs,    // [M][2]
    float* __restrict__ acc)            // [B][C][2][M]  (m contiguous -> coalesced atomics)
{
  const int b     = blockIdx.x / CHUNKS1;
  const int chunk = blockIdx.x % CHUNKS1;
  const int lane  = threadIdx.x & 63;   // mode
  const int wave  = threadIdx.x >> 6;   // channel group
  const int c0    = wave * 16;

  const float fx = freqs[2 * lane];
  const float fy = freqs[2 * lane + 1];

  const float*  xb = inputs + (size_t)b * NN * CC;
  const float2* cb = (const float2*)(coords + (size_t)b * NN * 2);

  float ar[16], ai[16];
#pragma unroll
  for (int j = 0; j < 16; ++j) { ar[j] = 0.f; ai[j] = 0.f; }

  const int n0 = chunk * PTS1;
  for (int n = n0; n < n0 + PTS1; ++n) {
    const float2 cc = cb[n];                       // broadcast (same addr all lanes)
    const float ph = TWO_PI * fmaf(cc.x, fx, cc.y * fy);
    float sn, cs;
    __sincosf(ph, &sn, &cs);
    const float4* xp = (const float4*)(xb + (size_t)n * CC + c0);  // broadcast per wave
#pragma unroll
    for (int q = 0; q < 4; ++q) {
      const float4 v = xp[q];
      ar[4*q+0] = fmaf(cs, v.x, ar[4*q+0]);  ai[4*q+0] = fmaf(-sn, v.x, ai[4*q+0]);
      ar[4*q+1] = fmaf(cs, v.y, ar[4*q+1]);  ai[4*q+1] = fmaf(-sn, v.y, ai[4*q+1]);
      ar[4*q+2] = fmaf(cs, v.z, ar[4*q+2]);  ai[4*q+2] = fmaf(-sn, v.z, ai[4*q+2]);
      ar[4*q+3] = fmaf(cs, v.w, ar[4*q+3]);  ai[4*q+3] = fmaf(-sn, v.w, ai[4*q+3]);
    }
  }

  float* ab = acc + (size_t)b * CC * 2 * MM;
#pragma unroll
  for (int j = 0; j < 16; ++j) {
    atomicAdd(ab + ((c0 + j) * 2 + 0) * MM + lane, ar[j]);  // lanes contiguous in m
    atomicAdd(ab + ((c0 + j) * 2 + 1) * MM + lane, ai[j]);
  }
}

// ---------------- Pass 2: mix + reconstruct ----------------
// out[b][n][c] = sum_m cos(ph)*mre[m][c] - sin(ph)*mim[m][c]
// mixed = (coeffs/N) * (wre + i*wim) staged in LDS per block.
#define CHUNKS2 256
#define PTS2 (NN / CHUNKS2) // 256 points per block; 1 point per thread

__global__ __launch_bounds__(256) void recon_kernel(
    const float* __restrict__ coords,   // [B][N][2]
    const float* __restrict__ wre,      // [M][C]
    const float* __restrict__ wim,      // [M][C]
    const float* __restrict__ freqs,    // [M][2]
    const float* __restrict__ acc,      // [B][C][2][M]
    float* __restrict__ out)            // [B][N][C]
{
  // +4 pad: keeps rows 16B-aligned for float4 reads, breaks setup-store bank pileup
  __shared__ float s_mre[MM][CC + 4];
  __shared__ float s_mim[MM][CC + 4];
  __shared__ float s_fx[MM], s_fy[MM];

  const int b     = blockIdx.x / CHUNKS2;
  const int chunk = blockIdx.x % CHUNKS2;
  const int tid   = threadIdx.x;

  if (tid < MM) { s_fx[tid] = freqs[2 * tid]; s_fy[tid] = freqs[2 * tid + 1]; }

  const float invN = 1.0f / (float)NN;
  const float* ab = acc + (size_t)b * CC * 2 * MM;
  for (int i = tid; i < MM * CC; i += 256) {
    const int m = i & (MM - 1);   // lanes contiguous in m -> coalesced acc reads
    const int c = i >> 6;
    const float cr = ab[(c * 2 + 0) * MM + m];
    const float ci = ab[(c * 2 + 1) * MM + m];
    const float wr = wre[m * CC + c];
    const float wi = wim[m * CC + c];
    s_mre[m][c] = (cr * wr - ci * wi) * invN;
    s_mim[m][c] = (cr * wi + ci * wr) * invN;
  }
  __syncthreads();

  const int n = chunk * PTS2 + tid;
  const float2 cc = ((const float2*)(coords + (size_t)b * NN * 2))[n];

  float o[CC];
#pragma unroll
  for (int c = 0; c < CC; ++c) o[c] = 0.f;

  for (int m = 0; m < MM; ++m) {
    const float ph = TWO_PI * fmaf(cc.x, s_fx[m], cc.y * s_fy[m]);
    float sn, cs;
    __sincosf(ph, &sn, &cs);
    const float4* pr  = (const float4*)(&s_mre[m][0]);  // broadcast b128 reads
    const float4* pim = (const float4*)(&s_mim[m][0]);
#pragma unroll
    for (int q = 0; q < 16; ++q) {
      const float4 rv = pr[q];
      const float4 iv = pim[q];
      o[4*q+0] = fmaf(cs, rv.x, fmaf(-sn, iv.x, o[4*q+0]));
      o[4*q+1] = fmaf(cs, rv.y, fmaf(-sn, iv.y, o[4*q+1]));
      o[4*q+2] = fmaf(cs, rv.z, fmaf(-sn, iv.z, o[4*q+2]));
      o[4*q+3] = fmaf(cs, rv.w, fmaf(-sn, iv.w, o[4*q+3]));
    }
  }

  float4* op = (float4*)(out + ((size_t)b * NN + n) * CC);
#pragma unroll
  for (int q = 0; q < 16; ++q) {
    op[q] = make_float4(o[4*q+0], o[4*q+1], o[4*q+2], o[4*q+3]);
  }
}

extern "C" void kernel_launch(void* const* d_in, const int* in_sizes, int n_in,
                              void* d_out, int out_size, void* d_ws, size_t ws_size,
                              hipStream_t stream) {
  const float* inputs = (const float*)d_in[0];
  const float* coords = (const float*)d_in[1];
  const float* wre    = (const float*)d_in[2];
  const float* wim    = (const float*)d_in[3];
  const float* freqs  = (const float*)d_in[4];
  float* out = (float*)d_out;
  float* acc = (float*)d_ws;   // [B][C][2][M] fp32 = 256 KB

  hipMemsetAsync(acc, 0, (size_t)BB * CC * 2 * MM * sizeof(float), stream);
  proj_kernel<<<dim3(BB * CHUNKS1), dim3(256), 0, stream>>>(inputs, coords, freqs, acc);
  recon_kernel<<<dim3(BB * CHUNKS2), dim3(256), 0, stream>>>(coords, wre, wim, freqs, acc, out);
}

// Round 2
// 286.289 us; speedup vs baseline: 2.1457x; 2.1457x over previous
//
#include <hip/hip_runtime.h>
#include <hip/hip_bf16.h>

#define BB 8
#define NN 65536
#define CC 64
#define MM 64

#define TWO_PI 6.283185307179586476925286766559f

typedef __attribute__((ext_vector_type(8))) short bf16x8;
typedef __attribute__((ext_vector_type(4))) float f32x4;
typedef unsigned int u32;
typedef unsigned short u16;

// pack two fp32 -> two bf16 (RNE) in one u32 (a in low half)
__device__ inline u32 pk_bf2(float a, float b) {
  __hip_bfloat162 h = __float22bfloat162_rn(make_float2(a, b));
  u32 r;
  __builtin_memcpy(&r, &h, 4);
  return r;
}

__device__ inline u16 sbf(float a) {
  __hip_bfloat16 h = __float2bfloat16(a);
  u16 r;
  __builtin_memcpy(&r, &h, 2);
  return r;
}

// ============================ Pass 1: projection =============================
// G[b][m'][c] = sum_n A1[m'][n] * x[n][c],  A1[m][n]=cos(ph), A1[m+64][n]=sin(ph)
// MFMA 16x16x32 bf16; out tile 128x64 per block-chunk, fp32 atomics into accg.
// LDS tiles XOR-swizzled in 16B chunks: slot = (k8 + row) & 7, pitch 64 bf16.
__global__ __launch_bounds__(256) void proj_mfma(
    const float* __restrict__ inputs,   // [B][N][C]
    const float* __restrict__ coords,   // [B][N][2]
    const float* __restrict__ freqs,    // [M][2]
    float* __restrict__ accg)           // [B][128][64] fp32
{
  __shared__ __align__(16) u16 As[128 * 64];  // basis [m'=0..127][k=0..63]
  __shared__ __align__(16) u16 Xs[64 * 64];   // x^T   [c =0..63 ][k=0..63]

  const int tid  = threadIdx.x;
  const int b    = blockIdx.x >> 7;
  const int nbase = (blockIdx.x & 127) * 512;
  const int lane = tid & 63;
  const int wave = tid >> 6;
  const int l15  = lane & 15;
  const int quad = lane >> 4;

  // basis staging role: one mode per lane, one point-group per wave
  const int bm = tid & 63;
  const int pg = tid >> 6;
  const float fx = freqs[2 * bm];
  const float fy = freqs[2 * bm + 1];

  // X staging role
  const int np = tid & 15;   // point-pair
  const int cq = tid >> 4;   // channel quad

  const float4* c4 = (const float4*)coords;
  const float4* x4 = (const float4*)inputs;

  f32x4 acc[2][4];
#pragma unroll
  for (int rt = 0; rt < 2; ++rt)
#pragma unroll
    for (int ct = 0; ct < 4; ++ct) acc[rt][ct] = (f32x4){0.f, 0.f, 0.f, 0.f};

  for (int s = 0; s < 8; ++s) {
    const int n0 = nbase + s * 64;

    // ---- stage basis: 16 points (2 b128 chunks) x 1 mode per thread ----
#pragma unroll
    for (int g = 0; g < 2; ++g) {
      const int k8 = pg * 2 + g;          // 8-point chunk index within step
      const int nb = n0 + k8 * 8;
      u32 cpk[4], spk[4];
#pragma unroll
      for (int jj = 0; jj < 4; ++jj) {
        const float4 cc = c4[(size_t)(b * NN + nb + jj * 2) >> 1];  // 2 points
        const float ph0 = TWO_PI * fmaf(cc.x, fx, cc.y * fy);
        const float ph1 = TWO_PI * fmaf(cc.z, fx, cc.w * fy);
        float s0, c0, s1, c1;
        __sincosf(ph0, &s0, &c0);
        __sincosf(ph1, &s1, &c1);
        cpk[jj] = pk_bf2(c0, c1);
        spk[jj] = pk_bf2(s0, s1);
      }
      *(uint4*)&As[bm * 64 + ((k8 + bm) & 7) * 8] =
          make_uint4(cpk[0], cpk[1], cpk[2], cpk[3]);
      const int rs = bm + 64;
      *(uint4*)&As[rs * 64 + ((k8 + rs) & 7) * 8] =
          make_uint4(spk[0], spk[1], spk[2], spk[3]);
    }

    // ---- stage X transposed: pairs (n,n+1) packed per channel ----
#pragma unroll
    for (int half = 0; half < 2; ++half) {
      const int k = half * 32 + 2 * np;
      const int n = n0 + k;
      const float4 x0 = x4[(size_t)(b * NN + n) * 16 + cq];
      const float4 x1 = x4[(size_t)(b * NN + n + 1) * 16 + cq];
      const int k8 = k >> 3, koff = k & 7;
      const float* p0 = (const float*)&x0;
      const float* p1 = (const float*)&x1;
#pragma unroll
      for (int j = 0; j < 4; ++j) {
        const int c = cq * 4 + j;
        *(u32*)&Xs[c * 64 + ((k8 + c) & 7) * 8 + koff] = pk_bf2(p0[j], p1[j]);
      }
    }
    __syncthreads();

    // ---- MFMA: wave handles rows 32w..32w+31 (2 tiles) x all 64 cols ----
#pragma unroll
    for (int kk = 0; kk < 2; ++kk) {
      const int k8q = kk * 4 + quad;
      const int r0 = wave * 32 + l15;
      const int r1 = r0 + 16;
      const bf16x8 a0 = *(const bf16x8*)&As[r0 * 64 + ((k8q + r0) & 7) * 8];
      const bf16x8 a1 = *(const bf16x8*)&As[r1 * 64 + ((k8q + r1) & 7) * 8];
      bf16x8 bfr[4];
#pragma unroll
      for (int ct = 0; ct < 4; ++ct) {
        const int c = ct * 16 + l15;
        bfr[ct] = *(const bf16x8*)&Xs[c * 64 + ((k8q + c) & 7) * 8];
      }
#pragma unroll
      for (int ct = 0; ct < 4; ++ct) {
        acc[0][ct] = __builtin_amdgcn_mfma_f32_16x16x32_bf16(a0, bfr[ct], acc[0][ct], 0, 0, 0);
        acc[1][ct] = __builtin_amdgcn_mfma_f32_16x16x32_bf16(a1, bfr[ct], acc[1][ct], 0, 0, 0);
      }
    }
    __syncthreads();
  }

  // ---- flush partials: fp32 atomics, lanes contiguous in c ----
  float* ab = accg + (size_t)b * 128 * 64;
#pragma unroll
  for (int rt = 0; rt < 2; ++rt)
#pragma unroll
    for (int ct = 0; ct < 4; ++ct)
#pragma unroll
      for (int r = 0; r < 4; ++r) {
        const int mrow = wave * 32 + rt * 16 + quad * 4 + r;
        const int c = ct * 16 + l15;
        atomicAdd(&ab[mrow * 64 + c], acc[rt][ct][r]);
      }
}

// ============================ Pass 1.5: mix =================================
// W2T[b][c][m]    = mre  = ( G[m]*wr + G[m+64]*wi)/N
// W2T[b][c][m+64] = -mim = ( G[m+64]*wr - G[m]*wi)/N     (bf16, m'-contiguous)
__global__ __launch_bounds__(256) void mix_kernel(
    const float* __restrict__ accg, const float* __restrict__ wre,
    const float* __restrict__ wim, u16* __restrict__ w2t)
{
  const int b = blockIdx.x;
  const float invN = 1.0f / (float)NN;
  const float* ab = accg + (size_t)b * 128 * 64;
  u16* wb_ = w2t + (size_t)b * 64 * 128;
  for (int idx = threadIdx.x; idx < MM * CC; idx += 256) {
    const int m = idx >> 6, c = idx & 63;
    const float gre = ab[m * 64 + c];
    const float gim = ab[(64 + m) * 64 + c];
    const float wr = wre[m * 64 + c], wi = wim[m * 64 + c];
    wb_[c * 128 + m]      = sbf((gre * wr + gim * wi) * invN);
    wb_[c * 128 + 64 + m] = sbf((gim * wr - gre * wi) * invN);
  }
}

// ============================ Pass 2: reconstruction ========================
// out[n][c] = sum_{m'} P[n][m'] * W2[m'][c],  P[n][m]=cos, P[n][m+64]=sin
// 128-point tiles, K=128; W2 fragments preloaded to VGPRs from global.
__global__ __launch_bounds__(256) void recon_mfma(
    const float* __restrict__ coords,   // [B][N][2]
    const u16* __restrict__ w2t,        // [B][64][128] bf16
    const float* __restrict__ freqs,    // [M][2]
    float* __restrict__ out)            // [B][N][C] fp32
{
  __shared__ __align__(16) u16 Ps[128 * 128];  // basis [n=0..127][m'=0..127]
  __shared__ float sfx[64], sfy[64];

  const int tid  = threadIdx.x;
  const int b    = blockIdx.x >> 7;
  const int tg   = blockIdx.x & 127;
  const int lane = tid & 63;
  const int wave = tid >> 6;
  const int l15  = lane & 15;
  const int quad = lane >> 4;

  if (tid < 64) { sfx[tid] = freqs[2 * tid]; sfy[tid] = freqs[2 * tid + 1]; }

  // preload all 16 W2 fragments (B-operand) from global
  bf16x8 wb[4][4];
#pragma unroll
  for (int kc = 0; kc < 4; ++kc)
#pragma unroll
    for (int ct = 0; ct < 4; ++ct)
      wb[kc][ct] = *(const bf16x8*)&w2t[((size_t)b * 64 + ct * 16 + l15) * 128 +
                                        kc * 32 + quad * 8];
  __syncthreads();

  const int p  = tid & 127;        // point within tile
  const int mg = (tid >> 7) * 32;  // 32-mode group
  const float2* c2 = (const float2*)coords;

  for (int t = 0; t < 4; ++t) {
    const int n0 = (tg * 4 + t) * 128;

    // ---- stage basis: 32 modes for one point per thread ----
    const float2 cc = c2[(size_t)b * NN + n0 + p];
#pragma unroll
    for (int g = 0; g < 4; ++g) {
      u32 cpk[4], spk[4];
#pragma unroll
      for (int jj = 0; jj < 4; ++jj) {
        const int m = mg + g * 8 + jj * 2;
        const float ph0 = TWO_PI * fmaf(cc.x, sfx[m], cc.y * sfy[m]);
        const float ph1 = TWO_PI * fmaf(cc.x, sfx[m + 1], cc.y * sfy[m + 1]);
        float s0, c0, s1, c1;
        __sincosf(ph0, &s0, &c0);
        __sincosf(ph1, &s1, &c1);
        cpk[jj] = pk_bf2(c0, c1);
        spk[jj] = pk_bf2(s0, s1);
      }
      const int k8c = (mg >> 3) + g;       // cos chunk 0..7
      const int k8s = k8c + 8;             // sin chunk 8..15
      *(uint4*)&Ps[p * 128 + ((k8c + p) & 15) * 8] =
          make_uint4(cpk[0], cpk[1], cpk[2], cpk[3]);
      *(uint4*)&Ps[p * 128 + ((k8s + p) & 15) * 8] =
          make_uint4(spk[0], spk[1], spk[2], spk[3]);
    }
    __syncthreads();

    // ---- MFMA: wave handles rows 32w..32w+31, K=128 ----
    f32x4 acc[2][4];
#pragma unroll
    for (int rt = 0; rt < 2; ++rt)
#pragma unroll
      for (int ct = 0; ct < 4; ++ct) acc[rt][ct] = (f32x4){0.f, 0.f, 0.f, 0.f};

#pragma unroll
    for (int kc = 0; kc < 4; ++kc) {
      const int k8q = kc * 4 + quad;
      const int r0 = wave * 32 + l15;
      const int r1 = r0 + 16;
      const bf16x8 a0 = *(const bf16x8*)&Ps[r0 * 128 + ((k8q + r0) & 15) * 8];
      const bf16x8 a1 = *(const bf16x8*)&Ps[r1 * 128 + ((k8q + r1) & 15) * 8];
#pragma unroll
      for (int ct = 0; ct < 4; ++ct) {
        acc[0][ct] = __builtin_amdgcn_mfma_f32_16x16x32_bf16(a0, wb[kc][ct], acc[0][ct], 0, 0, 0);
        acc[1][ct] = __builtin_amdgcn_mfma_f32_16x16x32_bf16(a1, wb[kc][ct], acc[1][ct], 0, 0, 0);
      }
    }

    // ---- store fp32 ----
    float* ob = out + ((size_t)b * NN + n0) * 64;
#pragma unroll
    for (int rt = 0; rt < 2; ++rt)
#pragma unroll
      for (int ct = 0; ct < 4; ++ct)
#pragma unroll
        for (int r = 0; r < 4; ++r) {
          const int row = wave * 32 + rt * 16 + quad * 4 + r;
          ob[row * 64 + ct * 16 + l15] = acc[rt][ct][r];
        }
    __syncthreads();
  }
}

extern "C" void kernel_launch(void* const* d_in, const int* in_sizes, int n_in,
                              void* d_out, int out_size, void* d_ws, size_t ws_size,
                              hipStream_t stream) {
  const float* inputs = (const float*)d_in[0];
  const float* coords = (const float*)d_in[1];
  const float* wre    = (const float*)d_in[2];
  const float* wim    = (const float*)d_in[3];
  const float* freqs  = (const float*)d_in[4];
  float* out = (float*)d_out;

  float* accg = (float*)d_ws;                                   // 256 KB fp32
  u16*   w2t  = (u16*)((char*)d_ws + (size_t)BB * 128 * 64 * 4); // 128 KB bf16

  hipMemsetAsync(accg, 0, (size_t)BB * 128 * 64 * sizeof(float), stream);
  proj_mfma<<<dim3(BB * 128), dim3(256), 0, stream>>>(inputs, coords, freqs, accg);
  mix_kernel<<<dim3(BB), dim3(256), 0, stream>>>(accg, wre, wim, w2t);
  recon_mfma<<<dim3(BB * 128), dim3(256), 0, stream>>>(coords, w2t, freqs, out);
}

// Round 3
// 266.304 us; speedup vs baseline: 2.3067x; 1.0750x over previous
//
#include <hip/hip_runtime.h>
#include <hip/hip_bf16.h>

#define BB 8
#define NN 65536
#define CC 64
#define MM 64

#define TWO_PI 6.283185307179586476925286766559f

typedef __attribute__((ext_vector_type(8))) short bf16x8;
typedef __attribute__((ext_vector_type(4))) float f32x4;
typedef unsigned int u32;
typedef unsigned short u16;

__device__ inline u32 pk_bf2(float a, float b) {
  __hip_bfloat162 h = __float22bfloat162_rn(make_float2(a, b));
  u32 r;
  __builtin_memcpy(&r, &h, 4);
  return r;
}

__device__ inline u16 sbf(float a) {
  __hip_bfloat16 h = __float2bfloat16(a);
  u16 r;
  __builtin_memcpy(&r, &h, 2);
  return r;
}

// ============================ Pass 1: projection =============================
// partial[blk][m'][c] = sum_{n in chunk} A1[m'][n] * x[n][c]
// A1[m][n]=cos(ph), A1[m+64][n]=sin(ph).  Double-buffered LDS, register
// prefetch, ONE barrier per 64-point step.  No atomics.
#define CH1 64
#define STEPS1 16   // 1024 points per block, 64 per step

__global__ __launch_bounds__(256) void proj_mfma(
    const float* __restrict__ inputs,   // [B][N][C]
    const float* __restrict__ coords,   // [B][N][2]
    const float* __restrict__ freqs,    // [M][2]
    float* __restrict__ partial)        // [BB*CH1][128][64] fp32
{
  __shared__ __align__(16) u16 As[2][128 * 64];  // basis [m'][k]  (swizzled)
  __shared__ __align__(16) u16 Xs[2][64 * 64];   // x^T   [c ][k]  (swizzled)

  const int tid   = threadIdx.x;
  const int b     = blockIdx.x >> 6;
  const int nbase = (blockIdx.x & 63) * 1024;
  const int lane  = tid & 63;
  const int wave  = tid >> 6;
  const int l15   = lane & 15;
  const int quad  = lane >> 4;

  // basis staging role: one mode per lane, one point-group per wave
  const int bm = tid & 63;
  const int pg = tid >> 6;
  const float fx = freqs[2 * bm];
  const float fy = freqs[2 * bm + 1];

  // X staging role (block-wide: cq 0..15 covers all 64 channels)
  const int np = tid & 15;
  const int cq = tid >> 4;

  const float4* c4 = (const float4*)coords;
  const float4* x4 = (const float4*)inputs;

  float4 cpre[2][4];   // prefetched coords (2 chunks x 4 point-pairs... x2 pts)
  float4 xpre[2][2];   // prefetched inputs (2 halves x 2 points)

  auto load_step = [&](int s) {
#pragma unroll
    for (int g = 0; g < 2; ++g) {
      const int nb = nbase + s * 64 + (pg * 2 + g) * 8;
#pragma unroll
      for (int jj = 0; jj < 4; ++jj)
        cpre[g][jj] = c4[(size_t)(b * NN + nb + jj * 2) >> 1];
    }
#pragma unroll
    for (int half = 0; half < 2; ++half) {
      const int n = nbase + s * 64 + half * 32 + 2 * np;
      xpre[half][0] = x4[(size_t)(b * NN + n) * 16 + cq];
      xpre[half][1] = x4[(size_t)(b * NN + n + 1) * 16 + cq];
    }
  };

  auto stage_step = [&](int buf) {
#pragma unroll
    for (int g = 0; g < 2; ++g) {
      const int k8 = pg * 2 + g;
      u32 cpk[4], spk[4];
#pragma unroll
      for (int jj = 0; jj < 4; ++jj) {
        const float4 cc = cpre[g][jj];
        const float ph0 = TWO_PI * fmaf(cc.x, fx, cc.y * fy);
        const float ph1 = TWO_PI * fmaf(cc.z, fx, cc.w * fy);
        float s0, c0, s1, c1;
        __sincosf(ph0, &s0, &c0);
        __sincosf(ph1, &s1, &c1);
        cpk[jj] = pk_bf2(c0, c1);
        spk[jj] = pk_bf2(s0, s1);
      }
      *(uint4*)&As[buf][bm * 64 + ((k8 + bm) & 7) * 8] =
          make_uint4(cpk[0], cpk[1], cpk[2], cpk[3]);
      const int rs = bm + 64;
      *(uint4*)&As[buf][rs * 64 + ((k8 + rs) & 7) * 8] =
          make_uint4(spk[0], spk[1], spk[2], spk[3]);
    }
#pragma unroll
    for (int half = 0; half < 2; ++half) {
      const int k = half * 32 + 2 * np;
      const int k8 = k >> 3, koff = k & 7;
      const float* p0 = (const float*)&xpre[half][0];
      const float* p1 = (const float*)&xpre[half][1];
#pragma unroll
      for (int j = 0; j < 4; ++j) {
        const int c = cq * 4 + j;
        *(u32*)&Xs[buf][c * 64 + ((k8 + c) & 7) * 8 + koff] = pk_bf2(p0[j], p1[j]);
      }
    }
  };

  f32x4 acc[2][4];
#pragma unroll
  for (int rt = 0; rt < 2; ++rt)
#pragma unroll
    for (int ct = 0; ct < 4; ++ct) acc[rt][ct] = (f32x4){0.f, 0.f, 0.f, 0.f};

  load_step(0);
  stage_step(0);
  __syncthreads();

  for (int s = 0; s < STEPS1; ++s) {
    const int cur = s & 1;
    if (s + 1 < STEPS1) load_step(s + 1);   // issue globals early

#pragma unroll
    for (int kk = 0; kk < 2; ++kk) {
      const int k8q = kk * 4 + quad;
      const int r0 = wave * 32 + l15;
      const int r1 = r0 + 16;
      const bf16x8 a0 = *(const bf16x8*)&As[cur][r0 * 64 + ((k8q + r0) & 7) * 8];
      const bf16x8 a1 = *(const bf16x8*)&As[cur][r1 * 64 + ((k8q + r1) & 7) * 8];
      bf16x8 bfr[4];
#pragma unroll
      for (int ct = 0; ct < 4; ++ct) {
        const int c = ct * 16 + l15;
        bfr[ct] = *(const bf16x8*)&Xs[cur][c * 64 + ((k8q + c) & 7) * 8];
      }
#pragma unroll
      for (int ct = 0; ct < 4; ++ct) {
        acc[0][ct] = __builtin_amdgcn_mfma_f32_16x16x32_bf16(a0, bfr[ct], acc[0][ct], 0, 0, 0);
        acc[1][ct] = __builtin_amdgcn_mfma_f32_16x16x32_bf16(a1, bfr[ct], acc[1][ct], 0, 0, 0);
      }
    }

    if (s + 1 < STEPS1) stage_step(1 - cur);  // write other buffer
    __syncthreads();                          // ONE barrier per step
  }

  // ---- flush: plain coalesced stores of this block's partial tile ----
  float* pb = partial + (size_t)blockIdx.x * (128 * 64);
#pragma unroll
  for (int rt = 0; rt < 2; ++rt)
#pragma unroll
    for (int ct = 0; ct < 4; ++ct)
#pragma unroll
      for (int r = 0; r < 4; ++r) {
        const int mrow = wave * 32 + rt * 16 + quad * 4 + r;
        const int c = ct * 16 + l15;
        pb[mrow * 64 + c] = acc[rt][ct][r];
      }
}

// ============================ Pass 1.5: reduce + mix ========================
// G[m'][c] = sum_{chunk} partial ;  W2T[b][c][m'] = {mre, -mim} in bf16
__global__ __launch_bounds__(256) void mix_kernel(
    const float* __restrict__ partial,  // [BB*CH1][128][64]
    const float* __restrict__ wre, const float* __restrict__ wim,
    u16* __restrict__ w2t)              // [BB][64][128]
{
  const int idx = blockIdx.x * 256 + threadIdx.x;  // 8*64*64 = 32768 total
  const int b = idx >> 12;
  const int m = (idx >> 6) & 63;
  const int c = idx & 63;
  const float* pb = partial + (size_t)b * CH1 * 8192;
  float gre = 0.f, gim = 0.f;
  for (int k = 0; k < CH1; ++k) {
    gre += pb[(size_t)k * 8192 + m * 64 + c];
    gim += pb[(size_t)k * 8192 + (64 + m) * 64 + c];
  }
  const float invN = 1.0f / (float)NN;
  const float wr = wre[m * 64 + c], wi = wim[m * 64 + c];
  u16* wb_ = w2t + (size_t)b * 64 * 128;
  wb_[c * 128 + m]      = sbf((gre * wr + gim * wi) * invN);
  wb_[c * 128 + 64 + m] = sbf((gim * wr - gre * wi) * invN);
}

// ============================ Pass 2: reconstruction ========================
// out[n][c] = sum_{m'} P[n][m'] * W2[m'][c].  Double-buffered Ps, coord
// prefetch, one barrier per 128-point tile.
#define TILES2 8   // 1024 points per block

__global__ __launch_bounds__(256) void recon_mfma(
    const float* __restrict__ coords,   // [B][N][2]
    const u16* __restrict__ w2t,        // [B][64][128] bf16
    const float* __restrict__ freqs,    // [M][2]
    float* __restrict__ out)            // [B][N][C] fp32
{
  __shared__ __align__(16) u16 Ps[2][128 * 128];  // 2 x 32 KB
  __shared__ float sfx[64], sfy[64];

  const int tid   = threadIdx.x;
  const int b     = blockIdx.x >> 6;
  const int nbase = (blockIdx.x & 63) * 1024;
  const int lane  = tid & 63;
  const int wave  = tid >> 6;
  const int l15   = lane & 15;
  const int quad  = lane >> 4;

  if (tid < 64) { sfx[tid] = freqs[2 * tid]; sfy[tid] = freqs[2 * tid + 1]; }

  // preload all 16 W2 fragments (B-operand) from global
  bf16x8 wb[4][4];
#pragma unroll
  for (int kc = 0; kc < 4; ++kc)
#pragma unroll
    for (int ct = 0; ct < 4; ++ct)
      wb[kc][ct] = *(const bf16x8*)&w2t[((size_t)b * 64 + ct * 16 + l15) * 128 +
                                        kc * 32 + quad * 8];
  __syncthreads();  // sfx/sfy visible

  const int p  = tid & 127;        // point within tile
  const int mg = (tid >> 7) * 32;  // 32-mode group
  const float2* c2 = (const float2*)coords;

  auto stage_tile = [&](int buf, float2 cc) {
#pragma unroll
    for (int g = 0; g < 4; ++g) {
      u32 cpk[4], spk[4];
#pragma unroll
      for (int jj = 0; jj < 4; ++jj) {
        const int m = mg + g * 8 + jj * 2;
        const float ph0 = TWO_PI * fmaf(cc.x, sfx[m], cc.y * sfy[m]);
        const float ph1 = TWO_PI * fmaf(cc.x, sfx[m + 1], cc.y * sfy[m + 1]);
        float s0, c0, s1, c1;
        __sincosf(ph0, &s0, &c0);
        __sincosf(ph1, &s1, &c1);
        cpk[jj] = pk_bf2(c0, c1);
        spk[jj] = pk_bf2(s0, s1);
      }
      const int k8c = (mg >> 3) + g;   // cos chunks 0..7
      const int k8s = k8c + 8;         // sin chunks 8..15
      *(uint4*)&Ps[buf][p * 128 + ((k8c + p) & 15) * 8] =
          make_uint4(cpk[0], cpk[1], cpk[2], cpk[3]);
      *(uint4*)&Ps[buf][p * 128 + ((k8s + p) & 15) * 8] =
          make_uint4(spk[0], spk[1], spk[2], spk[3]);
    }
  };

  float2 cpre = c2[(size_t)b * NN + nbase + p];
  stage_tile(0, cpre);
  __syncthreads();

  for (int t = 0; t < TILES2; ++t) {
    const int cur = t & 1;
    const int n0 = nbase + t * 128;

    float2 cnext;
    if (t + 1 < TILES2) cnext = c2[(size_t)b * NN + n0 + 128 + p];  // issue early

    f32x4 acc[2][4];
#pragma unroll
    for (int rt = 0; rt < 2; ++rt)
#pragma unroll
      for (int ct = 0; ct < 4; ++ct) acc[rt][ct] = (f32x4){0.f, 0.f, 0.f, 0.f};

#pragma unroll
    for (int kc = 0; kc < 4; ++kc) {
      const int k8q = kc * 4 + quad;
      const int r0 = wave * 32 + l15;
      const int r1 = r0 + 16;
      const bf16x8 a0 = *(const bf16x8*)&Ps[cur][r0 * 128 + ((k8q + r0) & 15) * 8];
      const bf16x8 a1 = *(const bf16x8*)&Ps[cur][r1 * 128 + ((k8q + r1) & 15) * 8];
#pragma unroll
      for (int ct = 0; ct < 4; ++ct) {
        acc[0][ct] = __builtin_amdgcn_mfma_f32_16x16x32_bf16(a0, wb[kc][ct], acc[0][ct], 0, 0, 0);
        acc[1][ct] = __builtin_amdgcn_mfma_f32_16x16x32_bf16(a1, wb[kc][ct], acc[1][ct], 0, 0, 0);
      }
    }

    if (t + 1 < TILES2) stage_tile(1 - cur, cnext);  // fill other buffer

    float* ob = out + ((size_t)b * NN + n0) * 64;
#pragma unroll
    for (int rt = 0; rt < 2; ++rt)
#pragma unroll
      for (int ct = 0; ct < 4; ++ct)
#pragma unroll
        for (int r = 0; r < 4; ++r) {
          const int row = wave * 32 + rt * 16 + quad * 4 + r;
          ob[row * 64 + ct * 16 + l15] = acc[rt][ct][r];
        }

    __syncthreads();  // ONE barrier per tile
  }
}

extern "C" void kernel_launch(void* const* d_in, const int* in_sizes, int n_in,
                              void* d_out, int out_size, void* d_ws, size_t ws_size,
                              hipStream_t stream) {
  const float* inputs = (const float*)d_in[0];
  const float* coords = (const float*)d_in[1];
  const float* wre    = (const float*)d_in[2];
  const float* wim    = (const float*)d_in[3];
  const float* freqs  = (const float*)d_in[4];
  float* out = (float*)d_out;

  float* partial = (float*)d_ws;  // [512][128][64] fp32 = 16 MB
  u16*   w2t     = (u16*)((char*)d_ws + (size_t)BB * CH1 * 128 * 64 * 4);

  proj_mfma<<<dim3(BB * CH1), dim3(256), 0, stream>>>(inputs, coords, freqs, partial);
  mix_kernel<<<dim3(128), dim3(256), 0, stream>>>(partial, wre, wim, w2t);
  recon_mfma<<<dim3(BB * CH1), dim3(256), 0, stream>>>(coords, w2t, freqs, out);
}

// Round 4
// 262.394 us; speedup vs baseline: 2.3411x; 1.0149x over previous
//
#include <hip/hip_runtime.h>
#include <hip/hip_bf16.h>

#define BB 8
#define NN 65536
#define CC 64
#define MM 64

typedef __attribute__((ext_vector_type(8))) short bf16x8;
typedef __attribute__((ext_vector_type(4))) float f32x4;
typedef unsigned int u32;
typedef unsigned short u16;

__device__ inline u32 pk_bf2(float a, float b) {
  __hip_bfloat162 h = __float22bfloat162_rn(make_float2(a, b));
  u32 r;
  __builtin_memcpy(&r, &h, 4);
  return r;
}

__device__ inline u16 sbf(float a) {
  __hip_bfloat16 h = __float2bfloat16(a);
  u16 r;
  __builtin_memcpy(&r, &h, 2);
  return r;
}

// t in REVOLUTIONS (= coord . freq). v_sin_f32/v_cos_f32 compute sin(2*pi*x);
// fract first keeps input in [0,1) (valid HW range), preserves value exactly.
__device__ inline void rsc(float t, float& sn, float& cs) {
  const float tf = __builtin_amdgcn_fractf(t);
  sn = __builtin_amdgcn_sinf(tf);
  cs = __builtin_amdgcn_cosf(tf);
}

// ============================ Pass 1: projection =============================
// partial[blk][m'][c] = sum_{n in chunk} A1[m'][n] * x[n][c]
// A1[m][n]=cos, A1[m+64][n]=sin. Double-buffered LDS, DISTANCE-2 register
// prefetch, one barrier per 64-point step, raw v_sin/v_cos.
#define CH1 64
#define STEPS1 16   // 1024 points per block, 64 per step

__global__ __launch_bounds__(256) void proj_mfma(
    const float* __restrict__ inputs,   // [B][N][C]
    const float* __restrict__ coords,   // [B][N][2]
    const float* __restrict__ freqs,    // [M][2]
    float* __restrict__ partial)        // [BB*CH1][128][64] fp32
{
  __shared__ __align__(16) u16 As[2][128 * 64];  // basis [m'][k] swizzled
  __shared__ __align__(16) u16 Xs[2][64 * 64];   // x^T   [c ][k] swizzled

  const int tid   = threadIdx.x;
  const int b     = blockIdx.x >> 6;
  const int nbase = (blockIdx.x & 63) * 1024;
  const int lane  = tid & 63;
  const int wave  = tid >> 6;
  const int l15   = lane & 15;
  const int quad  = lane >> 4;

  // basis staging role: point-pair q (k=2q,2q+1), mode octet mg (8 modes)
  const int q  = tid & 31;
  const int mg = tid >> 5;       // 0..7
  // X staging role
  const int np = tid & 15;
  const int cq = tid >> 4;       // 0..15

  float fqx[8], fqy[8];
#pragma unroll
  for (int mm = 0; mm < 8; ++mm) {
    fqx[mm] = freqs[2 * (mg * 8 + mm)];
    fqy[mm] = freqs[2 * (mg * 8 + mm) + 1];
  }

  const float4* c4 = (const float4*)coords;
  const float4* x4 = (const float4*)inputs;
  const size_t cbase = ((size_t)b * NN + nbase) >> 1;  // float4 units (2 pts each)
  const size_t xbase = ((size_t)b * NN + nbase) * 16;  // float4 units

  float4 cs_[2];       // coord prefetch slots (1 float4 = 2 points)
  float4 xs_[2][4];    // X prefetch slots (4 float4)

  auto do_load = [&](int s, int slot) {
    cs_[slot] = c4[cbase + (size_t)s * 32 + q];
#pragma unroll
    for (int half = 0; half < 2; ++half) {
      const int n = s * 64 + half * 32 + 2 * np;
      xs_[slot][half * 2 + 0] = x4[xbase + (size_t)n * 16 + cq];
      xs_[slot][half * 2 + 1] = x4[xbase + (size_t)(n + 1) * 16 + cq];
    }
  };

  auto do_stage = [&](int slot, int buf) {
    const float4 cp = cs_[slot];
    const int k8 = q >> 2;
    const int ko = (2 * q) & 7;
#pragma unroll
    for (int mm = 0; mm < 8; ++mm) {
      const int rc = mg * 8 + mm;
      const int rs = rc + 64;
      float s0, c0, s1, c1;
      rsc(fmaf(cp.x, fqx[mm], cp.y * fqy[mm]), s0, c0);
      rsc(fmaf(cp.z, fqx[mm], cp.w * fqy[mm]), s1, c1);
      *(u32*)&As[buf][rc * 64 + ((k8 + rc) & 7) * 8 + ko] = pk_bf2(c0, c1);
      *(u32*)&As[buf][rs * 64 + ((k8 + rs) & 7) * 8 + ko] = pk_bf2(s0, s1);
    }
#pragma unroll
    for (int half = 0; half < 2; ++half) {
      const int k = half * 32 + 2 * np;
      const int k8x = k >> 3, kox = k & 7;
      const float* p0 = (const float*)&xs_[slot][half * 2 + 0];
      const float* p1 = (const float*)&xs_[slot][half * 2 + 1];
#pragma unroll
      for (int j = 0; j < 4; ++j) {
        const int c = cq * 4 + j;
        *(u32*)&Xs[buf][c * 64 + ((k8x + c) & 7) * 8 + kox] = pk_bf2(p0[j], p1[j]);
      }
    }
  };

  f32x4 acc[2][4];
#pragma unroll
  for (int rt = 0; rt < 2; ++rt)
#pragma unroll
    for (int ct = 0; ct < 4; ++ct) acc[rt][ct] = (f32x4){0.f, 0.f, 0.f, 0.f};

  auto do_mfma = [&](int buf) {
#pragma unroll
    for (int kk = 0; kk < 2; ++kk) {
      const int k8q = kk * 4 + quad;
      const int r0 = wave * 32 + l15;
      const int r1 = r0 + 16;
      const bf16x8 a0 = *(const bf16x8*)&As[buf][r0 * 64 + ((k8q + r0) & 7) * 8];
      const bf16x8 a1 = *(const bf16x8*)&As[buf][r1 * 64 + ((k8q + r1) & 7) * 8];
      bf16x8 bfr[4];
#pragma unroll
      for (int ct = 0; ct < 4; ++ct) {
        const int c = ct * 16 + l15;
        bfr[ct] = *(const bf16x8*)&Xs[buf][c * 64 + ((k8q + c) & 7) * 8];
      }
#pragma unroll
      for (int ct = 0; ct < 4; ++ct) {
        acc[0][ct] = __builtin_amdgcn_mfma_f32_16x16x32_bf16(a0, bfr[ct], acc[0][ct], 0, 0, 0);
        acc[1][ct] = __builtin_amdgcn_mfma_f32_16x16x32_bf16(a1, bfr[ct], acc[1][ct], 0, 0, 0);
      }
    }
  };

  do_load(0, 0);
  do_load(1, 1);
  do_stage(0, 0);
  __syncthreads();

#pragma unroll
  for (int s = 0; s < STEPS1; ++s) {
    const int cur = s & 1;
    if (s + 2 < STEPS1) do_load(s + 2, cur);   // slot cur was consumed by stage(s)
    do_mfma(cur);
    if (s + 1 < STEPS1) do_stage(1 - cur, 1 - cur);
    __syncthreads();                            // one barrier per step
  }

  // ---- flush: coalesced stores of this block's partial tile ----
  float* pb = partial + (size_t)blockIdx.x * (128 * 64);
#pragma unroll
  for (int rt = 0; rt < 2; ++rt)
#pragma unroll
    for (int ct = 0; ct < 4; ++ct)
#pragma unroll
      for (int r = 0; r < 4; ++r) {
        const int mrow = wave * 32 + rt * 16 + quad * 4 + r;
        const int c = ct * 16 + l15;
        pb[mrow * 64 + c] = acc[rt][ct][r];
      }
}

// ============================ Pass 1.5: reduce + mix ========================
__global__ __launch_bounds__(256) void mix_kernel(
    const float* __restrict__ partial,  // [BB*CH1][128][64]
    const float* __restrict__ wre, const float* __restrict__ wim,
    u16* __restrict__ w2t)              // [BB][64][128]
{
  const int idx = blockIdx.x * 256 + threadIdx.x;  // 32768 total
  const int b = idx >> 12;
  const int m = (idx >> 6) & 63;
  const int c = idx & 63;
  const float* pb = partial + (size_t)b * CH1 * 8192;
  float gre = 0.f, gim = 0.f;
#pragma unroll 8
  for (int k = 0; k < CH1; ++k) {
    gre += pb[(size_t)k * 8192 + m * 64 + c];
    gim += pb[(size_t)k * 8192 + (64 + m) * 64 + c];
  }
  const float invN = 1.0f / (float)NN;
  const float wr = wre[m * 64 + c], wi = wim[m * 64 + c];
  u16* wb_ = w2t + (size_t)b * 64 * 128;
  wb_[c * 128 + m]      = sbf((gre * wr + gim * wi) * invN);
  wb_[c * 128 + 64 + m] = sbf((gim * wr - gre * wi) * invN);
}

// ============================ Pass 2: reconstruction ========================
// out[n][c] = sum_{m'} P[n][m'] * W2[m'][c]. Double-buffered Ps, distance-2
// coord prefetch, raw sincos, one barrier per 128-point tile.
#define TILES2 8   // 1024 points per block

__global__ __launch_bounds__(256) void recon_mfma(
    const float* __restrict__ coords,   // [B][N][2]
    const u16* __restrict__ w2t,        // [B][64][128] bf16
    const float* __restrict__ freqs,    // [M][2]
    float* __restrict__ out)            // [B][N][C] fp32
{
  __shared__ __align__(16) u16 Ps[2][128 * 128];  // 2 x 32 KB
  __shared__ float sfx[64], sfy[64];

  const int tid   = threadIdx.x;
  const int b     = blockIdx.x >> 6;
  const int nbase = (blockIdx.x & 63) * 1024;
  const int lane  = tid & 63;
  const int wave  = tid >> 6;
  const int l15   = lane & 15;
  const int quad  = lane >> 4;

  if (tid < 64) { sfx[tid] = freqs[2 * tid]; sfy[tid] = freqs[2 * tid + 1]; }

  const int p  = tid & 127;        // point within tile
  const int mg = (tid >> 7) * 32;  // 32-mode group
  const float2* c2 = (const float2*)coords;
  const size_t cb = (size_t)b * NN + nbase;

  // coord prefetch, distance 2
  float2 cpre[2];
  cpre[0] = c2[cb + p];
  cpre[1] = c2[cb + 128 + p];

  // preload all 16 W2 fragments (B-operand) from global
  bf16x8 wb[4][4];
#pragma unroll
  for (int kc = 0; kc < 4; ++kc)
#pragma unroll
    for (int ct = 0; ct < 4; ++ct)
      wb[kc][ct] = *(const bf16x8*)&w2t[((size_t)b * 64 + ct * 16 + l15) * 128 +
                                        kc * 32 + quad * 8];
  __syncthreads();  // sfx/sfy visible

  auto stage_tile = [&](int buf, float2 cc) {
#pragma unroll
    for (int g = 0; g < 4; ++g) {
      u32 cpk[4], spk[4];
#pragma unroll
      for (int jj = 0; jj < 4; ++jj) {
        const int m = mg + g * 8 + jj * 2;
        float s0, c0, s1, c1;
        rsc(fmaf(cc.x, sfx[m], cc.y * sfy[m]), s0, c0);
        rsc(fmaf(cc.x, sfx[m + 1], cc.y * sfy[m + 1]), s1, c1);
        cpk[jj] = pk_bf2(c0, c1);
        spk[jj] = pk_bf2(s0, s1);
      }
      const int k8c = (mg >> 3) + g;   // cos chunks 0..7
      const int k8s = k8c + 8;         // sin chunks 8..15
      *(uint4*)&Ps[buf][p * 128 + ((k8c + p) & 15) * 8] =
          make_uint4(cpk[0], cpk[1], cpk[2], cpk[3]);
      *(uint4*)&Ps[buf][p * 128 + ((k8s + p) & 15) * 8] =
          make_uint4(spk[0], spk[1], spk[2], spk[3]);
    }
  };

  stage_tile(0, cpre[0]);
  __syncthreads();

#pragma unroll
  for (int t = 0; t < TILES2; ++t) {
    const int cur = t & 1;
    if (t + 2 < TILES2) cpre[cur] = c2[cb + (size_t)(t + 2) * 128 + p];

    f32x4 acc[2][4];
#pragma unroll
    for (int rt = 0; rt < 2; ++rt)
#pragma unroll
      for (int ct = 0; ct < 4; ++ct) acc[rt][ct] = (f32x4){0.f, 0.f, 0.f, 0.f};

#pragma unroll
    for (int kc = 0; kc < 4; ++kc) {
      const int k8q = kc * 4 + quad;
      const int r0 = wave * 32 + l15;
      const int r1 = r0 + 16;
      const bf16x8 a0 = *(const bf16x8*)&Ps[cur][r0 * 128 + ((k8q + r0) & 15) * 8];
      const bf16x8 a1 = *(const bf16x8*)&Ps[cur][r1 * 128 + ((k8q + r1) & 15) * 8];
#pragma unroll
      for (int ct = 0; ct < 4; ++ct) {
        acc[0][ct] = __builtin_amdgcn_mfma_f32_16x16x32_bf16(a0, wb[kc][ct], acc[0][ct], 0, 0, 0);
        acc[1][ct] = __builtin_amdgcn_mfma_f32_16x16x32_bf16(a1, wb[kc][ct], acc[1][ct], 0, 0, 0);
      }
    }

    if (t + 1 < TILES2) stage_tile(1 - cur, cpre[1 - cur]);

    float* ob = out + (cb + (size_t)t * 128) * 64;
#pragma unroll
    for (int rt = 0; rt < 2; ++rt)
#pragma unroll
      for (int ct = 0; ct < 4; ++ct)
#pragma unroll
        for (int r = 0; r < 4; ++r) {
          const int row = wave * 32 + rt * 16 + quad * 4 + r;
          ob[row * 64 + ct * 16 + l15] = acc[rt][ct][r];
        }

    __syncthreads();  // one barrier per tile
  }
}

extern "C" void kernel_launch(void* const* d_in, const int* in_sizes, int n_in,
                              void* d_out, int out_size, void* d_ws, size_t ws_size,
                              hipStream_t stream) {
  const float* inputs = (const float*)d_in[0];
  const float* coords = (const float*)d_in[1];
  const float* wre    = (const float*)d_in[2];
  const float* wim    = (const float*)d_in[3];
  const float* freqs  = (const float*)d_in[4];
  float* out = (float*)d_out;

  float* partial = (float*)d_ws;  // [512][128][64] fp32 = 16 MB
  u16*   w2t     = (u16*)((char*)d_ws + (size_t)BB * CH1 * 128 * 64 * 4);

  proj_mfma<<<dim3(BB * CH1), dim3(256), 0, stream>>>(inputs, coords, freqs, partial);
  mix_kernel<<<dim3(128), dim3(256), 0, stream>>>(partial, wre, wim, w2t);
  recon_mfma<<<dim3(BB * CH1), dim3(256), 0, stream>>>(coords, w2t, freqs, out);
}